// Round 14
// baseline (249.201 us; speedup 1.0000x reference)
//
#include <hip/hip_runtime.h>
#include <math.h>

#define BB 8
#define LL 1024
#define DD 1024
#define KD 1024   // GEMM K depth (token-space GEMMs)
#define NM 32     // complex modes per channel
#define NCH 16    // chunks over L
#define CL 64     // chunk length (NCH*CL == LL)
#define NTOK (BB * LL)

typedef __bf16 bf16_t;
typedef __bf16 bf16x8 __attribute__((ext_vector_type(8)));
typedef __bf16 bf16x4 __attribute__((ext_vector_type(4)));
typedef float  f32x4  __attribute__((ext_vector_type(4)));

__device__ __forceinline__ float gelu_f(float z)
{
    float t = fmaf(0.044715f * z * z, z, z);
    return z / (1.f + expf(-1.5957691216f * t));
}

// ---------------- fused fp32 -> bf16 converts (x, in_W, gluW, outW) -----------
__global__ __launch_bounds__(256)
void f2b_all_kernel(const float* __restrict__ x,    bf16_t* __restrict__ xb,
                    const float* __restrict__ w0,   bf16_t* __restrict__ d0,
                    const float* __restrict__ w1,   bf16_t* __restrict__ d1,
                    const float* __restrict__ w2,   bf16_t* __restrict__ d2)
{
    int b = blockIdx.x;
    const float* s; bf16_t* d; int base;
    if (b < 8192)       { s = x;  d = xb; base = b; }
    else if (b < 9216)  { s = w0; d = d0; base = b - 8192; }
    else if (b < 11264) { s = w1; d = d1; base = b - 9216; }
    else                { s = w2; d = d2; base = b - 11264; }
    int i = (base * 256 + threadIdx.x) * 4;
    float4 f = *(const float4*)(s + i);
    bf16x4 o = { (bf16_t)f.x, (bf16_t)f.y, (bf16_t)f.z, (bf16_t)f.w };
    *(bf16x4*)(d + i) = o;
}

#define GLL(gp, lp) __builtin_amdgcn_global_load_lds( \
    (const __attribute__((address_space(1))) void*)(gp), \
    (__attribute__((address_space(3))) void*)(lp), 16, 0, 0)

// =============================================================================
// 128x128 GEMM, BK=64 double-buffered -- r5/r11/r13 verified.
//  (a) 8-granule XOR swizzle (conflicts 4.19M -> 0, verified r1/r4/r5)
//  (b) 2-phase double-buffer (stage(t+1) before compute(t))
//  (c) NEW r14: XCD-chunked bijective block swizzle (512 blocks, %8==0).
//      Consecutive WORK ITEMS (same by = A-panel sharers) are pinned to one
//      XCD's L2 -> panel fetched into 1 L2 instead of 8; cuts L3-latency
//      re-reads in a latency-bound kernel (22-28% MfmaUtil). Transform
//      refcheck-verified r6.
// MODE 0: bf16 out = acc + bias[m]            (in-proj, channel-major out)
// MODE 2: f32  out = acc + bias[n] + res[m,n] (out-proj + residual)
// =============================================================================
__device__ __forceinline__ void stage_tile(const bf16_t* __restrict__ Ag,
                                           const bf16_t* __restrict__ Bg,
                                           bf16_t* Asb, bf16_t* Bsb, int tid)
{
    #pragma unroll
    for (int p = 0; p < 4; ++p) {
        int e = p * 256 + tid;                    // 0..1023 (128 rows x 8 gran)
        int row = e >> 3, sc = ((e & 7) ^ (row & 7)) << 3;
        GLL(Ag + (size_t)row * KD + sc, Asb + e * 8);
    }
    #pragma unroll
    for (int p = 0; p < 4; ++p) {
        int e = p * 256 + tid;
        int row = e >> 3, sc = ((e & 7) ^ (row & 7)) << 3;
        GLL(Bg + (size_t)row * KD + sc, Bsb + e * 8);
    }
}

template<int MODE>
__global__ __launch_bounds__(256, 2)
void gemm_db_kernel(const bf16_t* __restrict__ A, const bf16_t* __restrict__ B,
                    const float* __restrict__ bias, const float* __restrict__ res,
                    void* __restrict__ outp, int ldo)
{
    __shared__ bf16_t As[2][128 * 64];
    __shared__ bf16_t Bs[2][128 * 64];
    const int tid = threadIdx.x;
    const int lane = tid & 63, w = tid >> 6;
    const int wy = w >> 1, wx = w & 1;
    const int lm = lane & 15;
    const int qq = lane >> 4;                     // quarter-wave index

    // XCD-chunked bijective swizzle (grid %8 == 0): HW bid k on XCD (k&7)
    // computes work item (k&7)*cpx + k/8 -> each XCD owns a contiguous chunk
    // of work items; consecutive work items share the A panel.
    const int nbx = gridDim.x;
    int bid = blockIdx.y * nbx + blockIdx.x;
    const int cpx = (gridDim.x * gridDim.y) >> 3;
    bid = (bid & 7) * cpx + (bid >> 3);
    const int m0 = (bid / nbx) << 7, n0 = (bid % nbx) << 7;

    const bf16_t* Ag = A + (size_t)m0 * KD;
    const bf16_t* Bg = B + (size_t)n0 * KD;
    f32x4 acc[4][4] = {};

    stage_tile(Ag, Bg, As[0], Bs[0], tid);
    __syncthreads();

    int buf = 0;
    #pragma unroll 1
    for (int t = 0; t < 16; ++t) {
        if (t + 1 < 16)
            stage_tile(Ag + (t + 1) * 64, Bg + (t + 1) * 64,
                       As[buf ^ 1], Bs[buf ^ 1], tid);
        #pragma unroll
        for (int kk = 0; kk < 2; ++kk) {
            bf16x8 af[4], bfr[4];
            const int g = (kk << 2) + qq;         // logical 16B granule 0..7
            #pragma unroll
            for (int i = 0; i < 4; ++i) {
                int row = (wy << 6) + (i << 4) + lm;
                af[i] = *(const bf16x8*)&As[buf][row * 64 + ((g ^ (row & 7)) << 3)];
            }
            #pragma unroll
            for (int j = 0; j < 4; ++j) {
                int row = (wx << 6) + (j << 4) + lm;
                bfr[j] = *(const bf16x8*)&Bs[buf][row * 64 + ((g ^ (row & 7)) << 3)];
            }
            #pragma unroll
            for (int i = 0; i < 4; ++i)
                #pragma unroll
                for (int j = 0; j < 4; ++j)
                    acc[i][j] = __builtin_amdgcn_mfma_f32_16x16x32_bf16(
                                    af[i], bfr[j], acc[i][j], 0, 0, 0);
        }
        __syncthreads();   // drains vmcnt(0)+lgkmcnt(0): t+1 staged, buf free
        buf ^= 1;
    }

    // ---- epilogue ----
    const int row4 = (lane >> 4) << 2;
    #pragma unroll
    for (int i = 0; i < 4; ++i) {
        #pragma unroll
        for (int r = 0; r < 4; ++r) {
            int m = m0 + (wy << 6) + (i << 4) + row4 + r;
            #pragma unroll
            for (int j = 0; j < 4; ++j) {
                int n = n0 + (wx << 6) + (j << 4) + lm;
                float v = acc[i][j][r];
                if (MODE == 0) {
                    ((bf16_t*)outp)[(size_t)m * ldo + n] = (bf16_t)(v + bias[m]);
                } else {
                    ((float*)outp)[(size_t)m * ldo + n] =
                        v + bias[n] + res[(size_t)m * ldo + n];
                }
            }
        }
    }
}

// =============================================================================
// Fused GLU GEMM (verified r13: 47.8 us, 719 TF): tile 128(tok) x 64(n),
// BK=32 dbuf, both B panels staged per K-tile, dual acc[4][2]; epilogue
// v=(a+ba)*sigmoid(g+bg). Grid (16,64) = 1024 blocks, LDS 32 KiB.
// NEW r14: XCD-chunked swizzle (A-panel sharers = consecutive work items).
// =============================================================================
__device__ __forceinline__ void stage_gluf(const bf16_t* __restrict__ Ag,
                                           const bf16_t* __restrict__ Ba,
                                           const bf16_t* __restrict__ Bg,
                                           bf16_t* Asb, bf16_t* Bab, bf16_t* Bgb,
                                           int tid)
{
    #pragma unroll
    for (int p = 0; p < 2; ++p) {
        int e = p * 256 + tid;                    // A: 128 rows x 4 granules
        int row = e >> 2, sg = (e & 3) ^ ((row >> 1) & 3);
        GLL(Ag + (size_t)row * KD + sg * 8, Asb + e * 8);
    }
    {
        int e = tid;                              // B_a: 64 rows x 4 granules
        int row = e >> 2, sg = (e & 3) ^ ((row >> 1) & 3);
        GLL(Ba + (size_t)row * KD + sg * 8, Bab + e * 8);
    }
    {
        int e = tid;                              // B_g: 64 rows x 4 granules
        int row = e >> 2, sg = (e & 3) ^ ((row >> 1) & 3);
        GLL(Bg + (size_t)row * KD + sg * 8, Bgb + e * 8);
    }
}

__global__ __launch_bounds__(256, 2)
void gluf_kernel(const bf16_t* __restrict__ A, const bf16_t* __restrict__ B,
                 const float* __restrict__ bias, bf16_t* __restrict__ outp)
{
    __shared__ bf16_t As[2][128 * 32];            // 16 KiB
    __shared__ bf16_t Bsa[2][64 * 32];            //  8 KiB
    __shared__ bf16_t Bsg[2][64 * 32];            //  8 KiB
    const int tid = threadIdx.x;
    const int lane = tid & 63, w = tid >> 6;
    const int wy = w >> 1, wx = w & 1;            // 2x2 waves: 64 tok x 32 n
    const int lm = lane & 15;
    const int qq = lane >> 4;                     // quarter-wave = K-granule

    // XCD-chunked bijective swizzle (1024 blocks, %8 == 0)
    const int nbx = gridDim.x;
    int bid = blockIdx.y * nbx + blockIdx.x;
    const int cpx = (gridDim.x * gridDim.y) >> 3;
    bid = (bid & 7) * cpx + (bid >> 3);
    const int m0 = (bid / nbx) << 7;              // token rows
    const int n0 = (bid % nbx) << 6;              // output cols (a side)

    const bf16_t* Ag  = A + (size_t)m0 * KD;
    const bf16_t* Bga = B + (size_t)n0 * KD;
    const bf16_t* Bgg = B + (size_t)(1024 + n0) * KD;

    f32x4 acc_a[4][2] = {};
    f32x4 acc_g[4][2] = {};

    stage_gluf(Ag, Bga, Bgg, As[0], Bsa[0], Bsg[0], tid);
    __syncthreads();

    int buf = 0;
    #pragma unroll 1
    for (int t = 0; t < 32; ++t) {
        if (t + 1 < 32)
            stage_gluf(Ag + (t + 1) * 32, Bga + (t + 1) * 32, Bgg + (t + 1) * 32,
                       As[buf ^ 1], Bsa[buf ^ 1], Bsg[buf ^ 1], tid);
        bf16x8 af[4], ba[2], bg[2];
        #pragma unroll
        for (int i = 0; i < 4; ++i) {
            int row = (wy << 6) + (i << 4) + lm;  // 0..127
            af[i] = *(const bf16x8*)&As[buf][row * 32
                                             + ((qq ^ ((row >> 1) & 3)) << 3)];
        }
        #pragma unroll
        for (int j = 0; j < 2; ++j) {
            int row = (wx << 5) + (j << 4) + lm;  // 0..63
            int off = row * 32 + ((qq ^ ((row >> 1) & 3)) << 3);
            ba[j] = *(const bf16x8*)&Bsa[buf][off];
            bg[j] = *(const bf16x8*)&Bsg[buf][off];
        }
        #pragma unroll
        for (int i = 0; i < 4; ++i)
            #pragma unroll
            for (int j = 0; j < 2; ++j) {
                acc_a[i][j] = __builtin_amdgcn_mfma_f32_16x16x32_bf16(
                                  af[i], ba[j], acc_a[i][j], 0, 0, 0);
                acc_g[i][j] = __builtin_amdgcn_mfma_f32_16x16x32_bf16(
                                  af[i], bg[j], acc_g[i][j], 0, 0, 0);
            }
        __syncthreads();   // drains vmcnt(0)+lgkmcnt(0): t+1 staged, buf free
        buf ^= 1;
    }

    const int row4 = (lane >> 4) << 2;
    #pragma unroll
    for (int i = 0; i < 4; ++i)
        #pragma unroll
        for (int r = 0; r < 4; ++r) {
            int m = m0 + (wy << 6) + (i << 4) + row4 + r;
            #pragma unroll
            for (int j = 0; j < 2; ++j) {
                int n = n0 + (wx << 5) + (j << 4) + lm;
                float a = acc_a[i][j][r] + bias[n];
                float g = acc_g[i][j][r] + bias[1024 + n];
                outp[(size_t)m * 1024 + n] = (bf16_t)(a / (1.f + expf(-g)));
            }
        }
}

// ---------------- genV + genTP merged (block-uniform branch) ------------------
// TP branch (verified r5): Vandermonde table E[d][n]=w_n^d via complex
// recurrence -- 1 sincos+exp per thread (32x fewer transcendentals than r4).
__global__ __launch_bounds__(64)
void genVTP_kernel(const float* __restrict__ log_dt, const float* __restrict__ lar,
                   const float* __restrict__ aim, const float* __restrict__ Cp,
                   const float* __restrict__ dskip,
                   bf16_t* __restrict__ V, bf16_t* __restrict__ TP)
{
    const int tid = threadIdx.x;
    if (blockIdx.x < DD / 2) {
        const int h = blockIdx.x * 2 + (tid >> 5);
        const int n = tid & 31;
        const float dt = expf(log_dt[h]);
        const float ardt = -expf(lar[h * NM + n]) * dt;
        const float aidt = aim[h * NM + n] * dt;
        float sn, cs;
        sincosf(aidt, &sn, &cs);
        float er = expf(ardt);
        float wr = er * cs, wi = er * sn;
        float inv = 1.f / fmaf(wr, wr, wi * wi);
        float vr = wr * inv, vi = -wi * inv;      // w^-1
        sincosf(63.f * aidt, &sn, &cs);
        er = expf(63.f * ardt);
        float pr = er * cs, pi = er * sn;         // w^63
        bf16_t* rowr = V + ((size_t)h * 64 + 2 * n) * 64;
        bf16_t* rowi = rowr + 64;
        #pragma unroll
        for (int c8 = 0; c8 < 8; ++c8) {
            bf16x8 rr, ri;
            #pragma unroll
            for (int e = 0; e < 8; ++e) {
                rr[e] = (bf16_t)pr; ri[e] = (bf16_t)pi;
                float t = fmaf(pr, vr, -pi * vi);
                pi = fmaf(pr, vi, pi * vr);
                pr = t;
            }
            *(bf16x8*)(rowr + c8 * 8) = rr;
            *(bf16x8*)(rowi + c8 * 8) = ri;
        }
        return;
    }
    // ---- TP branch ----
    __shared__ float cr_s[NM], ci_s[NM], K_s[CL];
    __shared__ float wr_s[NM], wi_s[NM], ardt_s[NM], aidt_s[NM];
    __shared__ float er_s[65 * 33], ei_s[65 * 33];   // E[d][n] = w_n^d, pad 33
    const int h = blockIdx.x - DD / 2;
    if (tid < NM) {
        int n = tid;
        const float dt = expf(log_dt[h]);
        float ar = -expf(lar[h * NM + n]);
        float ai = aim[h * NM + n];
        float sn, cs;
        sincosf(ai * dt, &sn, &cs);
        float er = expf(ar * dt);
        float wrr = er * cs, wii = er * sn;
        float Crr = Cp[(h * NM + n) * 2 + 0];
        float Cii = Cp[(h * NM + n) * 2 + 1];
        float nr = fmaf(Crr, wrr - 1.f, -Cii * wii);
        float ni = fmaf(Crr, wii, Cii * (wrr - 1.f));
        float inv = 2.f / fmaf(ar, ar, ai * ai);
        cr_s[n] = fmaf(nr, ar, ni * ai) * inv;
        ci_s[n] = fmaf(ni, ar, -nr * ai) * inv;
        wr_s[n] = wrr;  wi_s[n] = wii;
        ardt_s[n] = ar * dt;
        aidt_s[n] = ai * dt;
        er_s[n] = 1.f;  ei_s[n] = 0.f;            // row d = 0
    }
    __syncthreads();
    {   // table rows d = 1..64: half 0 -> 1..32, half 1 -> 33..64
        const int n = tid & 31;
        const int s = 1 + (tid >> 5) * 32;
        float sn, cs;
        sincosf(aidt_s[n] * (float)s, &sn, &cs);
        float e0 = expf(ardt_s[n] * (float)s);
        float pr = e0 * cs, pi = e0 * sn;
        const float wr = wr_s[n], wi = wi_s[n];
        int base = s * 33 + n;
        #pragma unroll
        for (int j = 0; j < 32; ++j) {
            er_s[base] = pr;  ei_s[base] = pi;
            float t0 = fmaf(pr, wr, -pi * wi);
            pi = fmaf(pr, wi, pi * wr);
            pr = t0;
            base += 33;
        }
    }
    __syncthreads();
    {   // K[d] = sum_n cr*Re(w^d) - ci*Im(w^d);  K[0] += D_skip
        const int d = tid;
        float kv = (d == 0) ? dskip[h] : 0.f;
        #pragma unroll
        for (int n = 0; n < NM; ++n) {
            kv = fmaf(cr_s[n], er_s[d * 33 + n], kv);
            kv = fmaf(-ci_s[n], ei_s[d * 33 + n], kv);
        }
        K_s[d] = kv;
    }
    __syncthreads();
    const int i = tid;
    bf16_t* row = TP + ((size_t)h * CL + i) * 128;
    #pragma unroll
    for (int c8 = 0; c8 < 8; ++c8) {
        bf16x8 v;
        #pragma unroll
        for (int e = 0; e < 8; ++e) {
            int l = c8 * 8 + e;
            v[e] = (l <= i) ? (bf16_t)K_s[i - l] : (bf16_t)0.f;
        }
        *(bf16x8*)(row + c8 * 8) = v;
    }
    #pragma unroll
    for (int c8 = 0; c8 < 8; ++c8) {
        bf16x8 v;
        #pragma unroll
        for (int q = 0; q < 4; ++q) {
            int n = c8 * 4 + q;
            float Wr = er_s[(i + 1) * 33 + n];    // w_n^(i+1) from table
            float Wi = ei_s[(i + 1) * 33 + n];
            v[2 * q]     = (bf16_t)(fmaf(cr_s[n], Wr, -ci_s[n] * Wi));
            v[2 * q + 1] = (bf16_t)(-fmaf(cr_s[n], Wi, ci_s[n] * Wr));
        }
        *(bf16x8*)(row + 64 + c8 * 8) = v;
    }
}

// ---------------- fused SSM: S=U@V^T -> scan (LDS) -> Y=[U|Sc]@TP^T, gelu -----
__global__ __launch_bounds__(256)
void ssm_fused_kernel(const bf16_t* __restrict__ u_ch, const bf16_t* __restrict__ V,
                      const bf16_t* __restrict__ TP,
                      const float* __restrict__ log_dt, const float* __restrict__ lar,
                      const float* __restrict__ aim, bf16_t* __restrict__ y_bi)
{
    __shared__ float  Sbc_s[128 * 64];
    __shared__ bf16_t Sc_s[128 * 64];
    const int h = blockIdx.x;
    const int tid = threadIdx.x;
    const int lane = tid & 63, w = tid >> 6;
    const int lm = lane & 15, ks = (lane >> 4) << 3;
    const bf16_t* U   = u_ch + (size_t)h * 8192;  // [128 batch][64 l]
    const bf16_t* Vh  = V    + (size_t)h * 4096;  // [64 comp][64 l]
    const bf16_t* TPh = TP   + (size_t)h * 8192;  // [64 i][128 k]

    bf16x8 af_u[2][2];
    #pragma unroll
    for (int im = 0; im < 2; ++im)
        #pragma unroll
        for (int kk = 0; kk < 2; ++kk)
            af_u[im][kk] = *(const bf16x8*)(U + (((w << 1) + im) * 16 + lm) * 64
                                            + kk * 32 + ks);

    // ---- G1: chunk-local end states ----
    f32x4 acc1[2][4] = {};
    #pragma unroll
    for (int kk = 0; kk < 2; ++kk) {
        bf16x8 bfr[4];
        #pragma unroll
        for (int jn = 0; jn < 4; ++jn)
            bfr[jn] = *(const bf16x8*)(Vh + (jn * 16 + lm) * 64 + kk * 32 + ks);
        #pragma unroll
        for (int im = 0; im < 2; ++im)
            #pragma unroll
            for (int jn = 0; jn < 4; ++jn)
                acc1[im][jn] = __builtin_amdgcn_mfma_f32_16x16x32_bf16(
                                   af_u[im][kk], bfr[jn], acc1[im][jn], 0, 0, 0);
    }
    const int r4 = (lane >> 4) << 2;
    #pragma unroll
    for (int im = 0; im < 2; ++im)
        #pragma unroll
        for (int jn = 0; jn < 4; ++jn)
            #pragma unroll
            for (int r = 0; r < 4; ++r)
                Sbc_s[(((w << 1) + im) * 16 + r4 + r) * 64 + jn * 16 + lm]
                    = acc1[im][jn][r];
    __syncthreads();

    // ---- scan over chunks: thread t -> (b = t>>5, n = t&31) ----
    {
        const int b = tid >> 5, n = tid & 31;
        const float dtv = expf(log_dt[h]);
        const float ardt = -expf(lar[h * NM + n]) * dtv;
        const float aidt = aim[h * NM + n] * dtv;
        float sn, cs;
        sincosf(64.f * aidt, &sn, &cs);
        float er = expf(64.f * ardt);
        const float gr = er * cs, gi = er * sn;   // w^CL
        float sr = 0.f, si = 0.f;
        for (int c = 0; c < NCH; ++c) {
            int idx = (b * 16 + c) * 64 + 2 * n;
            float lr = Sbc_s[idx], li = Sbc_s[idx + 1];
            Sc_s[idx]     = (bf16_t)sr;           // carry-in state for chunk c
            Sc_s[idx + 1] = (bf16_t)si;
            float t0 = fmaf(gr, sr, fmaf(-gi, si, lr));
            si = fmaf(gr, si, fmaf(gi, sr, li));
            sr = t0;
        }
    }
    __syncthreads();

    // ---- G3: Y = [U | Sc] @ TP^T, gelu ----
    f32x4 acc2[2][4] = {};
    #pragma unroll
    for (int kk = 0; kk < 4; ++kk) {
        bf16x8 af[2], bfr[4];
        #pragma unroll
        for (int im = 0; im < 2; ++im) {
            if (kk < 2)
                af[im] = af_u[im][kk];
            else
                af[im] = *(bf16x8*)&Sc_s[(((w << 1) + im) * 16 + lm) * 64
                                         + (kk - 2) * 32 + ks];
        }
        #pragma unroll
        for (int jn = 0; jn < 4; ++jn)
            bfr[jn] = *(const bf16x8*)(TPh + (jn * 16 + lm) * 128 + kk * 32 + ks);
        #pragma unroll
        for (int im = 0; im < 2; ++im)
            #pragma unroll
            for (int jn = 0; jn < 4; ++jn)
                acc2[im][jn] = __builtin_amdgcn_mfma_f32_16x16x32_bf16(
                                   af[im], bfr[jn], acc2[im][jn], 0, 0, 0);
    }
    bf16_t* out = y_bi + (size_t)h * 8192;        // [128 batch][64 i]
    #pragma unroll
    for (int im = 0; im < 2; ++im)
        #pragma unroll
        for (int jn = 0; jn < 4; ++jn)
            #pragma unroll
            for (int r = 0; r < 4; ++r) {
                int batch = ((w << 1) + im) * 16 + r4 + r;
                int i = jn * 16 + lm;
                out[batch * 64 + i] = (bf16_t)gelu_f(acc2[im][jn][r]);
            }
}

// ---------------- 64x64 bf16 tile transpose: dst[c][r] = src[r][c] ------------
__global__ __launch_bounds__(256)
void transpose_kernel(const bf16_t* __restrict__ src, bf16_t* __restrict__ dst,
                      int src_rows, int src_cols)
{
    __shared__ unsigned short tile[64][68];
    const int tid = threadIdx.x;
    const int c0 = blockIdx.x << 6, r0 = blockIdx.y << 6;
    const int r = tid >> 4, c4 = (tid & 15) << 2;
    #pragma unroll
    for (int p = 0; p < 4; ++p) {
        int rr = p * 16 + r;
        ushort4 v = *(const ushort4*)((const unsigned short*)src +
                                      (size_t)(r0 + rr) * src_cols + c0 + c4);
        *(ushort4*)&tile[rr][c4] = v;
    }
    __syncthreads();
    #pragma unroll
    for (int p = 0; p < 4; ++p) {
        int rr = p * 16 + r;                      // dst-row-local (src col)
        ushort4 v;
        v.x = tile[c4 + 0][rr];
        v.y = tile[c4 + 1][rr];
        v.z = tile[c4 + 2][rr];
        v.w = tile[c4 + 3][rr];
        *(ushort4*)((unsigned short*)dst + (size_t)(c0 + rr) * src_rows + r0 + c4) = v;
    }
}

extern "C" void kernel_launch(void* const* d_in, const int* in_sizes, int n_in,
                              void* d_out, int out_size, void* d_ws, size_t ws_size,
                              hipStream_t stream)
{
    (void)in_sizes; (void)n_in; (void)out_size; (void)ws_size;
    const float* x      = (const float*)d_in[0];
    const float* in_W   = (const float*)d_in[1];
    const float* in_b   = (const float*)d_in[2];
    const float* log_dt = (const float*)d_in[3];
    const float* Cp     = (const float*)d_in[4];
    const float* lar    = (const float*)d_in[5];
    const float* aim    = (const float*)d_in[6];
    const float* dsk    = (const float*)d_in[7];
    const float* gluW   = (const float*)d_in[8];
    const float* glub   = (const float*)d_in[9];
    const float* outW   = (const float*)d_in[10];
    const float* outb   = (const float*)d_in[11];

    // ws layout (56.6 MiB peak):
    //  [0,16M):  xb -> TP (after in-proj) -> y_tok (after ssm)
    //  [16,24M): V (dead after ssm) -> [16,32M): vb (fused-GLU output)
    //  [32,48M): u_ch (bf16, channel-major)
    //  [48M..):  wbin 2M | wbglu 4M | wbout 2M
    // d_out: y_bi bf16 (16M) -> final output
    char* ws = (char*)d_ws;
    bf16_t* xb    = (bf16_t*)(ws);
    bf16_t* TP    = (bf16_t*)(ws);
    bf16_t* y_tok = (bf16_t*)(ws);
    bf16_t* V     = (bf16_t*)(ws + 16777216);
    bf16_t* vb    = (bf16_t*)(ws + 16777216);
    bf16_t* u_ch  = (bf16_t*)(ws + 33554432);
    bf16_t* wbin  = (bf16_t*)(ws + 50331648);
    bf16_t* wbglu = (bf16_t*)(ws + 52428800);
    bf16_t* wbout = (bf16_t*)(ws + 56623104);
    bf16_t* y_bi  = (bf16_t*)d_out;

    f2b_all_kernel<<<dim3(12288), dim3(256), 0, stream>>>(
        x, xb, in_W, wbin, gluW, wbglu, outW, wbout);

    // in-proj, channel-major output: u_ch[h][token]
    gemm_db_kernel<0><<<dim3(NTOK / 128, DD / 128), dim3(256), 0, stream>>>(
        wbin, xb, in_b, nullptr, u_ch, NTOK);

    // SSM: param tables, then fused per-channel (G1 -> scan -> G3)
    genVTP_kernel<<<dim3(DD / 2 + DD), dim3(64), 0, stream>>>(
        log_dt, lar, aim, Cp, dsk, V, TP);
    ssm_fused_kernel<<<dim3(DD), dim3(256), 0, stream>>>(
        u_ch, V, TP, log_dt, lar, aim, y_bi);

    // back to token-major, then fused GLU GEMM (a & g panels + sigmoid epilogue)
    transpose_kernel<<<dim3(NTOK / 64, DD / 64), dim3(256), 0, stream>>>(y_bi, y_tok, DD, NTOK);
    gluf_kernel<<<dim3(1024 / 64, NTOK / 128), dim3(256), 0, stream>>>(
        y_tok, wbglu, glub, vb);

    // out-proj + residual
    gemm_db_kernel<2><<<dim3(DD / 128, NTOK / 128), dim3(256), 0, stream>>>(
        vb, wbout, outb, x, d_out, DD);
}

// Round 15
// 249.185 us; speedup vs baseline: 1.0001x; 1.0001x over previous
//
#include <hip/hip_runtime.h>
#include <math.h>

#define BB 8
#define LL 1024
#define DD 1024
#define KD 1024   // GEMM K depth (token-space GEMMs)
#define NM 32     // complex modes per channel
#define NCH 16    // chunks over L
#define CL 64     // chunk length (NCH*CL == LL)
#define NTOK (BB * LL)

typedef __bf16 bf16_t;
typedef __bf16 bf16x8 __attribute__((ext_vector_type(8)));
typedef __bf16 bf16x4 __attribute__((ext_vector_type(4)));
typedef float  f32x4  __attribute__((ext_vector_type(4)));

__device__ __forceinline__ float gelu_f(float z)
{
    float t = fmaf(0.044715f * z * z, z, z);
    return z / (1.f + expf(-1.5957691216f * t));
}

// ---------------- fused fp32 -> bf16 converts (x, in_W, gluW, outW) -----------
__global__ __launch_bounds__(256)
void f2b_all_kernel(const float* __restrict__ x,    bf16_t* __restrict__ xb,
                    const float* __restrict__ w0,   bf16_t* __restrict__ d0,
                    const float* __restrict__ w1,   bf16_t* __restrict__ d1,
                    const float* __restrict__ w2,   bf16_t* __restrict__ d2)
{
    int b = blockIdx.x;
    const float* s; bf16_t* d; int base;
    if (b < 8192)       { s = x;  d = xb; base = b; }
    else if (b < 9216)  { s = w0; d = d0; base = b - 8192; }
    else if (b < 11264) { s = w1; d = d1; base = b - 9216; }
    else                { s = w2; d = d2; base = b - 11264; }
    int i = (base * 256 + threadIdx.x) * 4;
    float4 f = *(const float4*)(s + i);
    bf16x4 o = { (bf16_t)f.x, (bf16_t)f.y, (bf16_t)f.z, (bf16_t)f.w };
    *(bf16x4*)(d + i) = o;
}

#define GLL(gp, lp) __builtin_amdgcn_global_load_lds( \
    (const __attribute__((address_space(1))) void*)(gp), \
    (__attribute__((address_space(3))) void*)(lp), 16, 0, 0)

// =============================================================================
// 128x128 GEMM, BK=64 double-buffered -- r5/r11/r13/r14 verified.
//  (a) 8-granule XOR swizzle (conflicts 4.19M -> 0)
//  (b) 2-phase double-buffer (stage(t+1) before compute(t))
//  (c) XCD-chunked bijective block swizzle (r14: FETCH 67.6->24.7 MB on gluf)
// MODE 0: bf16 out = acc + bias[m]            (in-proj, channel-major out)
// MODE 2: f32  out = acc + bias[n] + res[m,n] (out-proj + residual)
// =============================================================================
__device__ __forceinline__ void stage_tile(const bf16_t* __restrict__ Ag,
                                           const bf16_t* __restrict__ Bg,
                                           bf16_t* Asb, bf16_t* Bsb, int tid)
{
    #pragma unroll
    for (int p = 0; p < 4; ++p) {
        int e = p * 256 + tid;                    // 0..1023 (128 rows x 8 gran)
        int row = e >> 3, sc = ((e & 7) ^ (row & 7)) << 3;
        GLL(Ag + (size_t)row * KD + sc, Asb + e * 8);
    }
    #pragma unroll
    for (int p = 0; p < 4; ++p) {
        int e = p * 256 + tid;
        int row = e >> 3, sc = ((e & 7) ^ (row & 7)) << 3;
        GLL(Bg + (size_t)row * KD + sc, Bsb + e * 8);
    }
}

template<int MODE>
__global__ __launch_bounds__(256, 2)
void gemm_db_kernel(const bf16_t* __restrict__ A, const bf16_t* __restrict__ B,
                    const float* __restrict__ bias, const float* __restrict__ res,
                    void* __restrict__ outp, int ldo)
{
    __shared__ bf16_t As[2][128 * 64];
    __shared__ bf16_t Bs[2][128 * 64];
    const int tid = threadIdx.x;
    const int lane = tid & 63, w = tid >> 6;
    const int wy = w >> 1, wx = w & 1;
    const int lm = lane & 15;
    const int qq = lane >> 4;                     // quarter-wave index

    // XCD-chunked bijective swizzle (grid %8 == 0)
    const int nbx = gridDim.x;
    int bid = blockIdx.y * nbx + blockIdx.x;
    const int cpx = (gridDim.x * gridDim.y) >> 3;
    bid = (bid & 7) * cpx + (bid >> 3);
    const int m0 = (bid / nbx) << 7, n0 = (bid % nbx) << 7;

    const bf16_t* Ag = A + (size_t)m0 * KD;
    const bf16_t* Bg = B + (size_t)n0 * KD;
    f32x4 acc[4][4] = {};

    stage_tile(Ag, Bg, As[0], Bs[0], tid);
    __syncthreads();

    int buf = 0;
    #pragma unroll 1
    for (int t = 0; t < 16; ++t) {
        if (t + 1 < 16)
            stage_tile(Ag + (t + 1) * 64, Bg + (t + 1) * 64,
                       As[buf ^ 1], Bs[buf ^ 1], tid);
        #pragma unroll
        for (int kk = 0; kk < 2; ++kk) {
            bf16x8 af[4], bfr[4];
            const int g = (kk << 2) + qq;         // logical 16B granule 0..7
            #pragma unroll
            for (int i = 0; i < 4; ++i) {
                int row = (wy << 6) + (i << 4) + lm;
                af[i] = *(const bf16x8*)&As[buf][row * 64 + ((g ^ (row & 7)) << 3)];
            }
            #pragma unroll
            for (int j = 0; j < 4; ++j) {
                int row = (wx << 6) + (j << 4) + lm;
                bfr[j] = *(const bf16x8*)&Bs[buf][row * 64 + ((g ^ (row & 7)) << 3)];
            }
            #pragma unroll
            for (int i = 0; i < 4; ++i)
                #pragma unroll
                for (int j = 0; j < 4; ++j)
                    acc[i][j] = __builtin_amdgcn_mfma_f32_16x16x32_bf16(
                                    af[i], bfr[j], acc[i][j], 0, 0, 0);
        }
        __syncthreads();   // drains vmcnt(0)+lgkmcnt(0): t+1 staged, buf free
        buf ^= 1;
    }

    // ---- epilogue ----
    const int row4 = (lane >> 4) << 2;
    #pragma unroll
    for (int i = 0; i < 4; ++i) {
        #pragma unroll
        for (int r = 0; r < 4; ++r) {
            int m = m0 + (wy << 6) + (i << 4) + row4 + r;
            #pragma unroll
            for (int j = 0; j < 4; ++j) {
                int n = n0 + (wx << 6) + (j << 4) + lm;
                float v = acc[i][j][r];
                if (MODE == 0) {
                    ((bf16_t*)outp)[(size_t)m * ldo + n] = (bf16_t)(v + bias[m]);
                } else {
                    ((float*)outp)[(size_t)m * ldo + n] =
                        v + bias[n] + res[(size_t)m * ldo + n];
                }
            }
        }
    }
}

// =============================================================================
// Fused GLU GEMM (verified r13/r14: 47.5 us): tile 128(tok) x 64(n), BK=32
// dbuf, both B panels staged per K-tile, dual acc[4][2]; epilogue
// v=(a+ba)*sigmoid(g+bg). 1024 blocks, 32 KiB LDS, XCD swizzle.
// =============================================================================
__device__ __forceinline__ void stage_gluf(const bf16_t* __restrict__ Ag,
                                           const bf16_t* __restrict__ Ba,
                                           const bf16_t* __restrict__ Bg,
                                           bf16_t* Asb, bf16_t* Bab, bf16_t* Bgb,
                                           int tid)
{
    #pragma unroll
    for (int p = 0; p < 2; ++p) {
        int e = p * 256 + tid;                    // A: 128 rows x 4 granules
        int row = e >> 2, sg = (e & 3) ^ ((row >> 1) & 3);
        GLL(Ag + (size_t)row * KD + sg * 8, Asb + e * 8);
    }
    {
        int e = tid;                              // B_a: 64 rows x 4 granules
        int row = e >> 2, sg = (e & 3) ^ ((row >> 1) & 3);
        GLL(Ba + (size_t)row * KD + sg * 8, Bab + e * 8);
    }
    {
        int e = tid;                              // B_g: 64 rows x 4 granules
        int row = e >> 2, sg = (e & 3) ^ ((row >> 1) & 3);
        GLL(Bg + (size_t)row * KD + sg * 8, Bgb + e * 8);
    }
}

__global__ __launch_bounds__(256, 2)
void gluf_kernel(const bf16_t* __restrict__ A, const bf16_t* __restrict__ B,
                 const float* __restrict__ bias, bf16_t* __restrict__ outp)
{
    __shared__ bf16_t As[2][128 * 32];            // 16 KiB
    __shared__ bf16_t Bsa[2][64 * 32];            //  8 KiB
    __shared__ bf16_t Bsg[2][64 * 32];            //  8 KiB
    const int tid = threadIdx.x;
    const int lane = tid & 63, w = tid >> 6;
    const int wy = w >> 1, wx = w & 1;            // 2x2 waves: 64 tok x 32 n
    const int lm = lane & 15;
    const int qq = lane >> 4;                     // quarter-wave = K-granule

    // XCD-chunked bijective swizzle (1024 blocks, %8 == 0)
    const int nbx = gridDim.x;
    int bid = blockIdx.y * nbx + blockIdx.x;
    const int cpx = (gridDim.x * gridDim.y) >> 3;
    bid = (bid & 7) * cpx + (bid >> 3);
    const int m0 = (bid / nbx) << 7;              // token rows
    const int n0 = (bid % nbx) << 6;              // output cols (a side)

    const bf16_t* Ag  = A + (size_t)m0 * KD;
    const bf16_t* Bga = B + (size_t)n0 * KD;
    const bf16_t* Bgg = B + (size_t)(1024 + n0) * KD;

    f32x4 acc_a[4][2] = {};
    f32x4 acc_g[4][2] = {};

    stage_gluf(Ag, Bga, Bgg, As[0], Bsa[0], Bsg[0], tid);
    __syncthreads();

    int buf = 0;
    #pragma unroll 1
    for (int t = 0; t < 32; ++t) {
        if (t + 1 < 32)
            stage_gluf(Ag + (t + 1) * 32, Bga + (t + 1) * 32, Bgg + (t + 1) * 32,
                       As[buf ^ 1], Bsa[buf ^ 1], Bsg[buf ^ 1], tid);
        bf16x8 af[4], ba[2], bg[2];
        #pragma unroll
        for (int i = 0; i < 4; ++i) {
            int row = (wy << 6) + (i << 4) + lm;  // 0..127
            af[i] = *(const bf16x8*)&As[buf][row * 32
                                             + ((qq ^ ((row >> 1) & 3)) << 3)];
        }
        #pragma unroll
        for (int j = 0; j < 2; ++j) {
            int row = (wx << 5) + (j << 4) + lm;  // 0..63
            int off = row * 32 + ((qq ^ ((row >> 1) & 3)) << 3);
            ba[j] = *(const bf16x8*)&Bsa[buf][off];
            bg[j] = *(const bf16x8*)&Bsg[buf][off];
        }
        #pragma unroll
        for (int i = 0; i < 4; ++i)
            #pragma unroll
            for (int j = 0; j < 2; ++j) {
                acc_a[i][j] = __builtin_amdgcn_mfma_f32_16x16x32_bf16(
                                  af[i], ba[j], acc_a[i][j], 0, 0, 0);
                acc_g[i][j] = __builtin_amdgcn_mfma_f32_16x16x32_bf16(
                                  af[i], bg[j], acc_g[i][j], 0, 0, 0);
            }
        __syncthreads();   // drains vmcnt(0)+lgkmcnt(0): t+1 staged, buf free
        buf ^= 1;
    }

    const int row4 = (lane >> 4) << 2;
    #pragma unroll
    for (int i = 0; i < 4; ++i)
        #pragma unroll
        for (int r = 0; r < 4; ++r) {
            int m = m0 + (wy << 6) + (i << 4) + row4 + r;
            #pragma unroll
            for (int j = 0; j < 2; ++j) {
                int n = n0 + (wx << 5) + (j << 4) + lm;
                float a = acc_a[i][j][r] + bias[n];
                float g = acc_g[i][j][r] + bias[1024 + n];
                outp[(size_t)m * 1024 + n] = (bf16_t)(a / (1.f + expf(-g)));
            }
        }
}

// =============================================================================
// fused SSM (r15): inlined genVTP prologue builds V[h], TP[h] per block
// (tables in LDS scratch ALIASING Sbc_s -- dead until G1's epilogue; LDS stays
// 48 KiB / 3 blocks/CU), writes them to the same global V/TP buffers
// (same-CU write -> __syncthreads (vmcnt0 drain) -> read is L1-write-through
// safe), then runs the verified G1 -> scan -> G3 body UNCHANGED.
// Deletes the standalone 1536-block genVTP dispatch. E-table build split
// 8 segments x 8 rows across 256 threads (shorter recurrence than r5's 32-step
// = strictly more accurate).
// =============================================================================
__global__ __launch_bounds__(256)
void ssm_fused_kernel(const bf16_t* __restrict__ u_ch,
                      bf16_t* __restrict__ V, bf16_t* __restrict__ TP,
                      const float* __restrict__ log_dt, const float* __restrict__ lar,
                      const float* __restrict__ aim, const float* __restrict__ Cp,
                      const float* __restrict__ dskip, bf16_t* __restrict__ y_bi)
{
    __shared__ float  Sbc_s[128 * 64];            // 32 KiB (tables alias here)
    __shared__ bf16_t Sc_s[128 * 64];             // 16 KiB
    const int h = blockIdx.x;
    const int tid = threadIdx.x;
    const int lane = tid & 63, w = tid >> 6;
    const int lm = lane & 15, ks = (lane >> 4) << 3;
    const bf16_t* U   = u_ch + (size_t)h * 8192;  // [128 batch][64 l]
    bf16_t* Vg  = V  + (size_t)h * 4096;          // [64 comp][64 l]
    bf16_t* TPg = TP + (size_t)h * 8192;          // [64 i][128 k]

    // U fragments: independent global loads, issued early to overlap the build
    bf16x8 af_u[2][2];
    #pragma unroll
    for (int im = 0; im < 2; ++im)
        #pragma unroll
        for (int kk = 0; kk < 2; ++kk)
            af_u[im][kk] = *(const bf16x8*)(U + (((w << 1) + im) * 16 + lm) * 64
                                            + kk * 32 + ks);

    // ---- table scratch aliases Sbc_s (dead until G1 epilogue) ----
    float* er_s   = Sbc_s;                        // 65*33 = 2145 floats
    float* ei_s   = Sbc_s + 2176;
    float* cr_s   = Sbc_s + 4352;                 // 32 each
    float* ci_s   = cr_s + 32;
    float* wr_s   = cr_s + 64;
    float* wi_s   = cr_s + 96;
    float* ardt_s = cr_s + 128;
    float* aidt_s = cr_s + 160;
    float* K_s    = cr_s + 192;                   // 64

    // ---- phase A: per-mode params + E row 0 + V rows (genVTP code) ----
    if (tid < NM) {
        const int n = tid;
        const float dt = expf(log_dt[h]);
        float ar = -expf(lar[h * NM + n]);
        float ai = aim[h * NM + n];
        float sn, cs;
        sincosf(ai * dt, &sn, &cs);
        float er = expf(ar * dt);
        float wrr = er * cs, wii = er * sn;
        float Crr = Cp[(h * NM + n) * 2 + 0];
        float Cii = Cp[(h * NM + n) * 2 + 1];
        float nr = fmaf(Crr, wrr - 1.f, -Cii * wii);
        float ni = fmaf(Crr, wii, Cii * (wrr - 1.f));
        float inv = 2.f / fmaf(ar, ar, ai * ai);
        cr_s[n] = fmaf(nr, ar, ni * ai) * inv;
        ci_s[n] = fmaf(ni, ar, -nr * ai) * inv;
        wr_s[n] = wrr;  wi_s[n] = wii;
        ardt_s[n] = ar * dt;
        aidt_s[n] = ai * dt;
        er_s[n] = 1.f;  ei_s[n] = 0.f;            // E row d = 0
        // V rows 2n, 2n+1: w^(63-l) via recurrence from w^63 by w^-1
        float inv2 = 1.f / fmaf(wrr, wrr, wii * wii);
        float vr = wrr * inv2, vi = -wii * inv2;
        sincosf(63.f * (ai * dt), &sn, &cs);
        float e63 = expf(63.f * (ar * dt));
        float pr = e63 * cs, pi = e63 * sn;
        bf16_t* rowr = Vg + (size_t)(2 * n) * 64;
        bf16_t* rowi = rowr + 64;
        #pragma unroll
        for (int c8 = 0; c8 < 8; ++c8) {
            bf16x8 rr, ri;
            #pragma unroll
            for (int e = 0; e < 8; ++e) {
                rr[e] = (bf16_t)pr; ri[e] = (bf16_t)pi;
                float t = fmaf(pr, vr, -pi * vi);
                pi = fmaf(pr, vi, pi * vr);
                pr = t;
            }
            *(bf16x8*)(rowr + c8 * 8) = rr;
            *(bf16x8*)(rowi + c8 * 8) = ri;
        }
    }
    __syncthreads();
    // ---- phase B: E rows 1..64 (8 segments x 8-step recurrence) ----
    {
        const int n = tid & 31;
        const int s = 1 + (tid >> 5) * 8;
        float sn, cs;
        sincosf(aidt_s[n] * (float)s, &sn, &cs);
        float e0 = expf(ardt_s[n] * (float)s);
        float pr = e0 * cs, pi = e0 * sn;
        const float wr = wr_s[n], wi = wi_s[n];
        int base = s * 33 + n;
        #pragma unroll
        for (int j = 0; j < 8; ++j) {
            er_s[base] = pr;  ei_s[base] = pi;
            float t0 = fmaf(pr, wr, -pi * wi);
            pi = fmaf(pr, wi, pi * wr);
            pr = t0;
            base += 33;
        }
    }
    __syncthreads();
    // ---- phase C: K[d] = sum_n cr*Re(w^d) - ci*Im(w^d);  K[0] += D_skip ----
    if (tid < CL) {
        const int d = tid;
        float kv = (d == 0) ? dskip[h] : 0.f;
        #pragma unroll
        for (int n = 0; n < NM; ++n) {
            kv = fmaf(cr_s[n], er_s[d * 33 + n], kv);
            kv = fmaf(-ci_s[n], ei_s[d * 33 + n], kv);
        }
        K_s[d] = kv;
    }
    __syncthreads();
    // ---- phase D: TP rows (Toeplitz from K + W-part from E[i+1]) ----
    if (tid < CL) {
        const int i = tid;
        bf16_t* row = TPg + (size_t)i * 128;
        #pragma unroll
        for (int c8 = 0; c8 < 8; ++c8) {
            bf16x8 v;
            #pragma unroll
            for (int e = 0; e < 8; ++e) {
                int l = c8 * 8 + e;
                v[e] = (l <= i) ? (bf16_t)K_s[i - l] : (bf16_t)0.f;
            }
            *(bf16x8*)(row + c8 * 8) = v;
        }
        #pragma unroll
        for (int c8 = 0; c8 < 8; ++c8) {
            bf16x8 v;
            #pragma unroll
            for (int q = 0; q < 4; ++q) {
                int n = c8 * 4 + q;
                float Wr = er_s[(i + 1) * 33 + n];
                float Wi = ei_s[(i + 1) * 33 + n];
                v[2 * q]     = (bf16_t)(fmaf(cr_s[n], Wr, -ci_s[n] * Wi));
                v[2 * q + 1] = (bf16_t)(-fmaf(cr_s[n], Wi, ci_s[n] * Wr));
            }
            *(bf16x8*)(row + 64 + c8 * 8) = v;
        }
    }
    __syncthreads();   // drains vmcnt(0): V/TP global writes visible; tables dead

    // ---- G1: chunk-local end states (verified body, Vh -> Vg) ----
    f32x4 acc1[2][4] = {};
    #pragma unroll
    for (int kk = 0; kk < 2; ++kk) {
        bf16x8 bfr[4];
        #pragma unroll
        for (int jn = 0; jn < 4; ++jn)
            bfr[jn] = *(const bf16x8*)(Vg + (jn * 16 + lm) * 64 + kk * 32 + ks);
        #pragma unroll
        for (int im = 0; im < 2; ++im)
            #pragma unroll
            for (int jn = 0; jn < 4; ++jn)
                acc1[im][jn] = __builtin_amdgcn_mfma_f32_16x16x32_bf16(
                                   af_u[im][kk], bfr[jn], acc1[im][jn], 0, 0, 0);
    }
    const int r4 = (lane >> 4) << 2;
    #pragma unroll
    for (int im = 0; im < 2; ++im)
        #pragma unroll
        for (int jn = 0; jn < 4; ++jn)
            #pragma unroll
            for (int r = 0; r < 4; ++r)
                Sbc_s[(((w << 1) + im) * 16 + r4 + r) * 64 + jn * 16 + lm]
                    = acc1[im][jn][r];
    __syncthreads();

    // ---- scan over chunks: thread t -> (b = t>>5, n = t&31) ----
    {
        const int b = tid >> 5, n = tid & 31;
        const float dtv = expf(log_dt[h]);
        const float ardt = -expf(lar[h * NM + n]) * dtv;
        const float aidt = aim[h * NM + n] * dtv;
        float sn, cs;
        sincosf(64.f * aidt, &sn, &cs);
        float er = expf(64.f * ardt);
        const float gr = er * cs, gi = er * sn;   // w^CL
        float sr = 0.f, si = 0.f;
        for (int c = 0; c < NCH; ++c) {
            int idx = (b * 16 + c) * 64 + 2 * n;
            float lr = Sbc_s[idx], li = Sbc_s[idx + 1];
            Sc_s[idx]     = (bf16_t)sr;           // carry-in state for chunk c
            Sc_s[idx + 1] = (bf16_t)si;
            float t0 = fmaf(gr, sr, fmaf(-gi, si, lr));
            si = fmaf(gr, si, fmaf(gi, sr, li));
            sr = t0;
        }
    }
    __syncthreads();

    // ---- G3: Y = [U | Sc] @ TP^T, gelu (verified body, TPh -> TPg) ----
    f32x4 acc2[2][4] = {};
    #pragma unroll
    for (int kk = 0; kk < 4; ++kk) {
        bf16x8 af[2], bfr[4];
        #pragma unroll
        for (int im = 0; im < 2; ++im) {
            if (kk < 2)
                af[im] = af_u[im][kk];
            else
                af[im] = *(bf16x8*)&Sc_s[(((w << 1) + im) * 16 + lm) * 64
                                         + (kk - 2) * 32 + ks];
        }
        #pragma unroll
        for (int jn = 0; jn < 4; ++jn)
            bfr[jn] = *(const bf16x8*)(TPg + (jn * 16 + lm) * 128 + kk * 32 + ks);
        #pragma unroll
        for (int im = 0; im < 2; ++im)
            #pragma unroll
            for (int jn = 0; jn < 4; ++jn)
                acc2[im][jn] = __builtin_amdgcn_mfma_f32_16x16x32_bf16(
                                   af[im], bfr[jn], acc2[im][jn], 0, 0, 0);
    }
    bf16_t* out = y_bi + (size_t)h * 8192;        // [128 batch][64 i]
    #pragma unroll
    for (int im = 0; im < 2; ++im)
        #pragma unroll
        for (int jn = 0; jn < 4; ++jn)
            #pragma unroll
            for (int r = 0; r < 4; ++r) {
                int batch = ((w << 1) + im) * 16 + r4 + r;
                int i = jn * 16 + lm;
                out[batch * 64 + i] = (bf16_t)gelu_f(acc2[im][jn][r]);
            }
}

// ---------------- 64x64 bf16 tile transpose: dst[c][r] = src[r][c] ------------
__global__ __launch_bounds__(256)
void transpose_kernel(const bf16_t* __restrict__ src, bf16_t* __restrict__ dst,
                      int src_rows, int src_cols)
{
    __shared__ unsigned short tile[64][68];
    const int tid = threadIdx.x;
    const int c0 = blockIdx.x << 6, r0 = blockIdx.y << 6;
    const int r = tid >> 4, c4 = (tid & 15) << 2;
    #pragma unroll
    for (int p = 0; p < 4; ++p) {
        int rr = p * 16 + r;
        ushort4 v = *(const ushort4*)((const unsigned short*)src +
                                      (size_t)(r0 + rr) * src_cols + c0 + c4);
        *(ushort4*)&tile[rr][c4] = v;
    }
    __syncthreads();
    #pragma unroll
    for (int p = 0; p < 4; ++p) {
        int rr = p * 16 + r;                      // dst-row-local (src col)
        ushort4 v;
        v.x = tile[c4 + 0][rr];
        v.y = tile[c4 + 1][rr];
        v.z = tile[c4 + 2][rr];
        v.w = tile[c4 + 3][rr];
        *(ushort4*)((unsigned short*)dst + (size_t)(c0 + rr) * src_rows + r0 + c4) = v;
    }
}

extern "C" void kernel_launch(void* const* d_in, const int* in_sizes, int n_in,
                              void* d_out, int out_size, void* d_ws, size_t ws_size,
                              hipStream_t stream)
{
    (void)in_sizes; (void)n_in; (void)out_size; (void)ws_size;
    const float* x      = (const float*)d_in[0];
    const float* in_W   = (const float*)d_in[1];
    const float* in_b   = (const float*)d_in[2];
    const float* log_dt = (const float*)d_in[3];
    const float* Cp     = (const float*)d_in[4];
    const float* lar    = (const float*)d_in[5];
    const float* aim    = (const float*)d_in[6];
    const float* dsk    = (const float*)d_in[7];
    const float* gluW   = (const float*)d_in[8];
    const float* glub   = (const float*)d_in[9];
    const float* outW   = (const float*)d_in[10];
    const float* outb   = (const float*)d_in[11];

    // ws layout (56.6 MiB peak):
    //  [0,16M):  xb -> TP (ssm scratch) -> y_tok (after ssm)
    //  [16,24M): V (ssm scratch, dead after) -> [16,32M): vb (fused-GLU out)
    //  [32,48M): u_ch (bf16, channel-major)
    //  [48M..):  wbin 2M | wbglu 4M | wbout 2M
    // d_out: y_bi bf16 (16M) -> final output
    char* ws = (char*)d_ws;
    bf16_t* xb    = (bf16_t*)(ws);
    bf16_t* TP    = (bf16_t*)(ws);
    bf16_t* y_tok = (bf16_t*)(ws);
    bf16_t* V     = (bf16_t*)(ws + 16777216);
    bf16_t* vb    = (bf16_t*)(ws + 16777216);
    bf16_t* u_ch  = (bf16_t*)(ws + 33554432);
    bf16_t* wbin  = (bf16_t*)(ws + 50331648);
    bf16_t* wbglu = (bf16_t*)(ws + 52428800);
    bf16_t* wbout = (bf16_t*)(ws + 56623104);
    bf16_t* y_bi  = (bf16_t*)d_out;

    f2b_all_kernel<<<dim3(12288), dim3(256), 0, stream>>>(
        x, xb, in_W, wbin, gluW, wbglu, outW, wbout);

    // in-proj, channel-major output: u_ch[h][token]
    gemm_db_kernel<0><<<dim3(NTOK / 128, DD / 128), dim3(256), 0, stream>>>(
        wbin, xb, in_b, nullptr, u_ch, NTOK);

    // fused SSM: per-channel table build (inlined genVTP) + G1 -> scan -> G3
    ssm_fused_kernel<<<dim3(DD), dim3(256), 0, stream>>>(
        u_ch, V, TP, log_dt, lar, aim, Cp, dsk, y_bi);

    // back to token-major, then fused GLU GEMM (a & g panels + sigmoid epilogue)
    transpose_kernel<<<dim3(NTOK / 64, DD / 64), dim3(256), 0, stream>>>(y_bi, y_tok, DD, NTOK);
    gluf_kernel<<<dim3(1024 / 64, NTOK / 128), dim3(256), 0, stream>>>(
        y_tok, wbglu, glub, vb);

    // out-proj + residual
    gemm_db_kernel<2><<<dim3(DD / 128, NTOK / 128), dim3(256), 0, stream>>>(
        vb, wbout, outb, x, d_out, DD);
}